// Round 2
// baseline (1754.045 us; speedup 1.0000x reference)
//
#include <hip/hip_runtime.h>
#include <math.h>

#define BATCH   64
#define SEQLEN  128
#define EMBED   512
#define HID     1024
#define NSTEP   127
#define OUT0    65
#define NOUT    62
#define R_GX    4          // gx ring depth (slots of one timestep each)

typedef unsigned short ushort_t;
typedef __attribute__((ext_vector_type(8))) __bf16 bf16x8;
typedef __attribute__((ext_vector_type(4))) float  f32x4;

__device__ __forceinline__ float sigmoidf_(float x) { return 1.f / (1.f + expf(-x)); }

__device__ __forceinline__ ushort_t f2bf(float f) {
    unsigned u = __builtin_bit_cast(unsigned, f);
    unsigned r = (u + 0x7FFFu + ((u >> 16) & 1u)) >> 16;   // round-to-nearest-even
    return (ushort_t)r;
}
__device__ __forceinline__ float bf2f(ushort_t s) {
    unsigned u = ((unsigned)s) << 16;
    return __builtin_bit_cast(float, u);
}

// split 8 consecutive floats into bf16-hi / bf16-lo fragments
__device__ __forceinline__ void split8(const float* __restrict__ src, bf16x8& hv, bf16x8& lv) {
    float4 f0 = *(const float4*)src;
    float4 f1 = *(const float4*)(src + 4);
    float fv[8] = { f0.x, f0.y, f0.z, f0.w, f1.x, f1.y, f1.z, f1.w };
    #pragma unroll
    for (int i = 0; i < 8; ++i) {
        ushort_t hs = f2bf(fv[i]);
        ushort_t ls = f2bf(fv[i] - bf2f(hs));
        hv[i] = __builtin_bit_cast(__bf16, hs);
        lv[i] = __builtin_bit_cast(__bf16, ls);
    }
}

// 12 MFMAs: bf16x3 scheme (ah*bh + al*bh + ah*bl) for 2 M-tiles x 2 N-tiles
__device__ __forceinline__ void mfma12(
    bf16x8 ah0, bf16x8 al0, bf16x8 ah1, bf16x8 al1,
    bf16x8 bh0, bf16x8 bl0, bf16x8 bh1, bf16x8 bl1,
    f32x4 (&acc)[2][2])
{
    acc[0][0] = __builtin_amdgcn_mfma_f32_16x16x32_bf16(ah0, bh0, acc[0][0], 0, 0, 0);
    acc[0][1] = __builtin_amdgcn_mfma_f32_16x16x32_bf16(ah0, bh1, acc[0][1], 0, 0, 0);
    acc[1][0] = __builtin_amdgcn_mfma_f32_16x16x32_bf16(ah1, bh0, acc[1][0], 0, 0, 0);
    acc[1][1] = __builtin_amdgcn_mfma_f32_16x16x32_bf16(ah1, bh1, acc[1][1], 0, 0, 0);
    acc[0][0] = __builtin_amdgcn_mfma_f32_16x16x32_bf16(al0, bh0, acc[0][0], 0, 0, 0);
    acc[0][1] = __builtin_amdgcn_mfma_f32_16x16x32_bf16(al0, bh1, acc[0][1], 0, 0, 0);
    acc[1][0] = __builtin_amdgcn_mfma_f32_16x16x32_bf16(al1, bh0, acc[1][0], 0, 0, 0);
    acc[1][1] = __builtin_amdgcn_mfma_f32_16x16x32_bf16(al1, bh1, acc[1][1], 0, 0, 0);
    acc[0][0] = __builtin_amdgcn_mfma_f32_16x16x32_bf16(ah0, bl0, acc[0][0], 0, 0, 0);
    acc[0][1] = __builtin_amdgcn_mfma_f32_16x16x32_bf16(ah0, bl1, acc[0][1], 0, 0, 0);
    acc[1][0] = __builtin_amdgcn_mfma_f32_16x16x32_bf16(ah1, bl0, acc[1][0], 0, 0, 0);
    acc[1][1] = __builtin_amdgcn_mfma_f32_16x16x32_bf16(ah1, bl1, acc[1][1], 0, 0, 0);
}

// ===================== MFMA path prep (unchanged layouts) =====================

__global__ __launch_bounds__(256) void init_mfma(
    const float* __restrict__ h0, const float* __restrict__ c0,
    float* __restrict__ cT, ushort_t* __restrict__ hf_hi, ushort_t* __restrict__ hf_lo)
{
    int id = blockIdx.x * 256 + threadIdx.x;   // u*64+b
    int u = id >> 6, b = id & 63;
    cT[id] = c0[b * HID + u];
    float h = h0[b * HID + u];
    ushort_t hs = f2bf(h);
    ushort_t ls = f2bf(h - bf2f(hs));
    size_t idx = (((size_t)(u >> 5)) * 4 + (b >> 4)) * 512
               + ((((u & 31) >> 3) * 16) + (b & 15)) * 8 + (u & 7);
    hf_hi[idx] = hs;
    hf_lo[idx] = ls;
}

__global__ __launch_bounds__(256) void embed_frag(
    const int* __restrict__ prob, const float* __restrict__ embed,
    ushort_t* __restrict__ xf_hi, ushort_t* __restrict__ xf_lo)
{
    int t = blockIdx.x;
    for (int e = threadIdx.x; e < 4096; e += 256) {
        int b  = e >> 6;         // 0..63
        int kb = e & 63;         // k-block of 8
        int k  = kb * 8;
        int tok = prob[b * SEQLEN + t];
        const float* row = embed + (size_t)tok * EMBED + k;
        bf16x8 hv, lv;
        split8(row, hv, lv);
        size_t idx = (((size_t)t * 16 + (kb >> 2)) * 4 + (b >> 4)) * 512
                   + (((kb & 3) * 16) + (b & 15)) * 8;
        *(bf16x8*)(xf_hi + idx) = hv;
        *(bf16x8*)(xf_lo + idx) = lv;
    }
}

// ===================== fused producer/consumer persistent kernel =====================
// 256 blocks x 512 thr (8 waves: wn = w&1 (N-half, 2 N-tiles), kq = w>>1 (K-quarter)).
// bid < 128: CONSUMER — units u0=bid*8 (32 gate rows = 2 M-tiles). h-GEMM only;
//   W_hh bf16-hi/lo A-fragments held in REGISTERS (128 VGPR/wave, static indices);
//   LDS = 24 KB reduce scratch only. Per-K-quarter arrival counters gcnt[4]
//   (quarter q written by blocks bid>>5==q) replace the single go flag.
// bid >= 128: PRODUCER p=bid-128 — computes gates_x for consumer p into gx ring
//   (R_GX=4 slots), throttled on consumer progress (gcnt[3]); gx handoff uses
//   agent-scope atomics (L2-bypass) since ring slots are address-reused.
// hf keeps full per-t history (fresh addresses -> plain coalesced loads are safe;
// same release scheme as the harness-verified r13 kernel).

#define LDB(PH, PL, KS, S) { \
    const size_t o_ = (size_t)(KS) * 2048; \
    bh##S##0 = *(const bf16x8*)((PH) + o_);        bl##S##0 = *(const bf16x8*)((PL) + o_); \
    bh##S##1 = *(const bf16x8*)((PH) + o_ + 512);  bl##S##1 = *(const bf16x8*)((PL) + o_ + 512); }

#define MK(KS, S) mfma12(Ah##KS##_0, Al##KS##_0, Ah##KS##_1, Al##KS##_1, \
                         bh##S##0, bl##S##0, bh##S##1, bl##S##1, acc);
#define XM(KS, S) mfma12(Xh##KS##_0, Xl##KS##_0, Xh##KS##_1, Xl##KS##_1, \
                         bh##S##0, bl##S##0, bh##S##1, bl##S##1, acc);

#define LOADW(KS) split8(wrow0 + (KS) * 32, Ah##KS##_0, Al##KS##_0); \
                  split8(wrow1 + (KS) * 32, Ah##KS##_1, Al##KS##_1);
#define LOADX(KS) split8(xrow0 + (KS) * 32, Xh##KS##_0, Xl##KS##_0); \
                  split8(xrow1 + (KS) * 32, Xh##KS##_1, Xl##KS##_1);

// K-reduce across the 4 K-quarter waves (per N-half), via 24 KB LDS scratch.
#define KREDUCE() \
    if (kq >= 2) { _Pragma("unroll") for (int a = 0; a < 4; ++a) \
        *(f32x4*)&lds[(((wn * 2 + (kq - 2)) * 4 + a) * 64 + L) * 4] = acc[a >> 1][a & 1]; } \
    __syncthreads(); \
    if (kq < 2) { _Pragma("unroll") for (int a = 0; a < 4; ++a) \
        acc[a >> 1][a & 1] += *(const f32x4*)&lds[(((wn * 2 + kq) * 4 + a) * 64 + L) * 4]; } \
    if (kq == 1) { _Pragma("unroll") for (int a = 0; a < 4; ++a) \
        *(f32x4*)&lds[4096 + ((wn * 4 + a) * 64 + L) * 4] = acc[a >> 1][a & 1]; } \
    __syncthreads(); \
    if (kq == 0) { _Pragma("unroll") for (int a = 0; a < 4; ++a) \
        acc[a >> 1][a & 1] += *(const f32x4*)&lds[4096 + ((wn * 4 + a) * 64 + L) * 4]; }

__global__ __launch_bounds__(512, 2) void lstm_fused(
    const ushort_t* __restrict__ xf_hi, const ushort_t* __restrict__ xf_lo,
    ushort_t* __restrict__ hf_hi, ushort_t* __restrict__ hf_lo,
    const float* __restrict__ cT,
    const float* __restrict__ w_ih, const float* __restrict__ w_hh,
    const float* __restrict__ b_ih, const float* __restrict__ b_hh,
    const float* __restrict__ w_ans, float* __restrict__ pout,
    float* __restrict__ gx, int* __restrict__ bar)
{
    __shared__ float lds[6144];          // redA 16 KB + redB 8 KB
    const int tid = threadIdx.x;
    const int bid = blockIdx.x;
    const int w   = tid >> 6;            // 0..7
    const int wn  = w & 1;               // N-half (2 N-tiles of 16)
    const int kq  = w >> 1;              // K-quarter 0..3
    const int L   = tid & 63;
    const int n   = L & 15;
    const int q   = L >> 4;

    // bar[qtr*16]: consumer arrival counter per unit-quarter (one line each)
    // bar[256 + p*4]: producer p progress

    if (bid < 128) {
        // ========================= CONSUMER =========================
        const int u0 = bid * 8;
        const int ul = n >> 2, gate = n & 3;

        // one-time: W_hh -> A-frag registers (this wave's K-quarter, both M-tiles)
        bf16x8 Ah0_0, Al0_0, Ah0_1, Al0_1, Ah1_0, Al1_0, Ah1_1, Al1_1;
        bf16x8 Ah2_0, Al2_0, Ah2_1, Al2_1, Ah3_0, Al3_0, Ah3_1, Al3_1;
        bf16x8 Ah4_0, Al4_0, Ah4_1, Al4_1, Ah5_0, Al5_0, Ah5_1, Al5_1;
        bf16x8 Ah6_0, Al6_0, Ah6_1, Al6_1, Ah7_0, Al7_0, Ah7_1, Al7_1;
        {
            const float* wrow0 = w_hh + ((size_t)gate * HID + u0 + ul) * HID + kq * 256 + q * 8;
            const float* wrow1 = wrow0 + (size_t)4 * HID;
            LOADW(0) LOADW(1) LOADW(2) LOADW(3) LOADW(4) LOADW(5) LOADW(6) LOADW(7)
        }

        // per-lane state (meaningful for kq==0 waves; harmless elsewhere)
        float c[2][2], bs[2][4], wans[2];
        #pragma unroll
        for (int mt = 0; mt < 2; ++mt) {
            int ug = u0 + mt * 4 + q;
            #pragma unroll
            for (int ntl = 0; ntl < 2; ++ntl)
                c[mt][ntl] = cT[(size_t)ug * 64 + wn * 32 + ntl * 16 + n];
            #pragma unroll
            for (int j = 0; j < 4; ++j)
                bs[mt][j] = b_ih[j * HID + ug] + b_hh[j * HID + ug];
            wans[mt] = w_ans[ug];
        }

        int  lastSeen = 0;
        int* prog_me  = bar + 256 + bid * 4;
        int* gc_me    = bar + kq * 16;

        for (int t = 0; t < NSTEP; ++t) {
            // gx readiness (rare after warmup: producer runs several steps ahead)
            if (kq == 0 && lastSeen < t + 1) {
                int v;
                while ((v = __hip_atomic_load(prog_me, __ATOMIC_RELAXED,
                                              __HIP_MEMORY_SCOPE_AGENT)) < t + 1)
                    __builtin_amdgcn_s_sleep(2);
                lastSeen = v;
                __builtin_amdgcn_fence(__ATOMIC_ACQUIRE, "workgroup");
            }
            // wait for this K-quarter of h(t)
            if (t > 0) {
                while (__hip_atomic_load(gc_me, __ATOMIC_RELAXED,
                                         __HIP_MEMORY_SCOPE_AGENT) < 32 * t)
                    __builtin_amdgcn_s_sleep(1);
                __builtin_amdgcn_fence(__ATOMIC_ACQUIRE, "workgroup");
            }

            f32x4 acc[2][2];
            #pragma unroll
            for (int a = 0; a < 4; ++a) acc[a >> 1][a & 1] = (f32x4){0.f, 0.f, 0.f, 0.f};

            // ---- h phase: 8 ksteps, A from regs, B 2-deep pipelined ----
            const ushort_t* hb = hf_hi + (((size_t)t * 32 + kq * 8) * 4 + wn * 2) * 512 + L * 8;
            const ushort_t* lb = hf_lo + (((size_t)t * 32 + kq * 8) * 4 + wn * 2) * 512 + L * 8;
            bf16x8 bhA0, blA0, bhA1, blA1, bhB0, blB0, bhB1, blB1;
            LDB(hb, lb, 0, A)
            LDB(hb, lb, 1, B)  MK(0, A)
            LDB(hb, lb, 2, A)  MK(1, B)
            LDB(hb, lb, 3, B)  MK(2, A)
            LDB(hb, lb, 4, A)  MK(3, B)
            LDB(hb, lb, 5, B)  MK(4, A)
            LDB(hb, lb, 6, A)  MK(5, B)
            LDB(hb, lb, 7, B)  MK(6, A)
                               MK(7, B)

            // ---- gx partial loads (L2-bypass atomics; latency hides under reduce) ----
            f32x4 gxr[2][2];
            if (kq == 0) {
                const size_t gb = ((size_t)(t & (R_GX - 1)) * 128 + bid) * 8;
                #pragma unroll
                for (int mt = 0; mt < 2; ++mt)
                    #pragma unroll
                    for (int ntl = 0; ntl < 2; ++ntl) {
                        size_t off = ((gb + mt * 4 + q) * 64 + wn * 32 + ntl * 16 + n) * 4;
                        #pragma unroll
                        for (int j = 0; j < 4; ++j)
                            gxr[mt][ntl][j] = __hip_atomic_load(&gx[off + j],
                                __ATOMIC_RELAXED, __HIP_MEMORY_SCOPE_AGENT);
                    }
            }

            KREDUCE()

            if (kq == 0) {
                // ---- finalize: lane owns units {u0+q, u0+4+q} x batches {wn*32+n, wn*32+16+n} ----
                float pl0 = 0.f, pl1 = 0.f;
                #pragma unroll
                for (int mt = 0; mt < 2; ++mt)
                    #pragma unroll
                    for (int ntl = 0; ntl < 2; ++ntl) {
                        f32x4 g = acc[mt][ntl];
                        float ig = sigmoidf_(g[0] + gxr[mt][ntl][0] + bs[mt][0]);
                        float fg = sigmoidf_(g[1] + gxr[mt][ntl][1] + bs[mt][1]);
                        float gg = tanhf    (g[2] + gxr[mt][ntl][2] + bs[mt][2]);
                        float og = sigmoidf_(g[3] + gxr[mt][ntl][3] + bs[mt][3]);
                        float cn = fg * c[mt][ntl] + ig * gg;
                        c[mt][ntl] = cn;
                        float hn = og * tanhf(cn);

                        int ug = u0 + mt * 4 + q;
                        int bg = wn * 32 + ntl * 16 + n;
                        ushort_t hs = f2bf(hn);
                        ushort_t ls = f2bf(hn - bf2f(hs));
                        size_t idx = (((size_t)(t + 1) * 32 + (ug >> 5)) * 4 + (bg >> 4)) * 512
                                   + ((((ug & 31) >> 3) * 16) + (bg & 15)) * 8 + (ug & 7);
                        __hip_atomic_store(&hf_hi[idx], hs, __ATOMIC_RELAXED,
                                           __HIP_MEMORY_SCOPE_AGENT);
                        __hip_atomic_store(&hf_lo[idx], ls, __ATOMIC_RELAXED,
                                           __HIP_MEMORY_SCOPE_AGENT);
                        float pv = hn * wans[mt];
                        if (ntl == 0) pl0 += pv; else pl1 += pv;
                    }
                pl0 += __shfl_xor(pl0, 16, 64); pl0 += __shfl_xor(pl0, 32, 64);
                pl1 += __shfl_xor(pl1, 16, 64); pl1 += __shfl_xor(pl1, 32, 64);
                if (t >= OUT0 && q == 0) {
                    pout[((size_t)(t - OUT0) * 128 + bid) * 64 + wn * 32 + n]      = pl0;
                    pout[((size_t)(t - OUT0) * 128 + bid) * 64 + wn * 32 + 16 + n] = pl1;
                }
            }

            if (t == NSTEP - 1) break;
            __syncthreads();   // drains producer stores (vmcnt 0) before arrive
            if (tid == 0)
                __hip_atomic_fetch_add(bar + (bid >> 5) * 16, 1, __ATOMIC_RELAXED,
                                       __HIP_MEMORY_SCOPE_AGENT);
        }
    } else {
        // ========================= PRODUCER =========================
        const int p   = bid - 128;
        const int u0p = p * 8;
        const int ul = n >> 2, gate = n & 3;

        bf16x8 Xh0_0, Xl0_0, Xh0_1, Xl0_1, Xh1_0, Xl1_0, Xh1_1, Xl1_1;
        bf16x8 Xh2_0, Xl2_0, Xh2_1, Xl2_1, Xh3_0, Xl3_0, Xh3_1, Xl3_1;
        {
            const float* xrow0 = w_ih + ((size_t)gate * HID + u0p + ul) * EMBED + kq * 128 + q * 8;
            const float* xrow1 = xrow0 + (size_t)4 * EMBED;
            LOADX(0) LOADX(1) LOADX(2) LOADX(3)
        }

        int* prog_me = bar + 256 + p * 4;

        for (int t = 0; t < NSTEP; ++t) {
            // ring-slot throttle: slot t&3 free once quarter-3 consumers completed
            // step t-3 (which transitively implies all quarters completed t-4,
            // i.e. all reads of this slot's previous use are done).
            if (t >= R_GX - 1)
                while (__hip_atomic_load(bar + 48, __ATOMIC_RELAXED,
                                         __HIP_MEMORY_SCOPE_AGENT) < 32 * (t - R_GX + 2))
                    __builtin_amdgcn_s_sleep(4);

            f32x4 acc[2][2];
            #pragma unroll
            for (int a = 0; a < 4; ++a) acc[a >> 1][a & 1] = (f32x4){0.f, 0.f, 0.f, 0.f};

            const ushort_t* xb = xf_hi + (((size_t)t * 16 + kq * 4) * 4 + wn * 2) * 512 + L * 8;
            const ushort_t* xl = xf_lo + (((size_t)t * 16 + kq * 4) * 4 + wn * 2) * 512 + L * 8;
            bf16x8 bhA0, blA0, bhA1, blA1, bhB0, blB0, bhB1, blB1;
            LDB(xb, xl, 0, A)
            LDB(xb, xl, 1, B)  XM(0, A)
            LDB(xb, xl, 2, A)  XM(1, B)
            LDB(xb, xl, 3, B)  XM(2, A)
                               XM(3, B)

            KREDUCE()

            if (kq == 0) {
                const size_t gb = ((size_t)(t & (R_GX - 1)) * 128 + p) * 8;
                #pragma unroll
                for (int mt = 0; mt < 2; ++mt)
                    #pragma unroll
                    for (int ntl = 0; ntl < 2; ++ntl) {
                        size_t off = ((gb + mt * 4 + q) * 64 + wn * 32 + ntl * 16 + n) * 4;
                        #pragma unroll
                        for (int j = 0; j < 4; ++j)
                            __hip_atomic_store(&gx[off + j], acc[mt][ntl][j],
                                __ATOMIC_RELAXED, __HIP_MEMORY_SCOPE_AGENT);
                    }
            }
            __syncthreads();   // drain gx stores before publishing
            if (tid == 0)
                __hip_atomic_fetch_add(prog_me, 1, __ATOMIC_RELAXED,
                                       __HIP_MEMORY_SCOPE_AGENT);
        }
    }
}

// out[b][col] = sum over 128 block partials + bias.
__global__ __launch_bounds__(256) void finalize_mfma(
    const float* __restrict__ pout, const float* __restrict__ b_ans,
    float* __restrict__ out)
{
    __shared__ float r[256];
    int col = blockIdx.x;
    int tid = threadIdx.x;
    int b = tid & 63, qq = tid >> 6;
    float s = 0.f;
    for (int i = qq; i < 128; i += 4)
        s += pout[((size_t)col * 128 + i) * 64 + b];
    r[tid] = s;
    __syncthreads();
    if (tid < 64)
        out[tid * NOUT + col] = r[tid] + r[64 + tid] + r[128 + tid] + r[192 + tid]
                              + b_ans[0];
}

// ===================== round-9 proven fallback path =====================
#define NBLK    512
#define NTHR    512
#define REDA_OFF 12288
#define REDB_OFF 14336
#define REDC_OFF 15360
#define C_OFF    15872
#define HEAD_OFF 16000
#define LDS_FLOATS 16128

__global__ __launch_bounds__(256) void init_state(
    const float* __restrict__ h0, const float* __restrict__ c0,
    float* __restrict__ hT, float* __restrict__ cT)
{
    int id = blockIdx.x * 256 + threadIdx.x;
    int u = id >> 6, b = id & 63;
    hT[id] = h0[b * HID + u];
    cT[id] = c0[b * HID + u];
}

__global__ __launch_bounds__(256) void embed_transpose(
    const int* __restrict__ prob, const float* __restrict__ embed,
    float* __restrict__ xT)
{
    __shared__ float xe[64 * 132];
    int t = blockIdx.x;
    int tid = threadIdx.x;
    for (int kt = 0; kt < 4; ++kt) {
        #pragma unroll
        for (int i = 0; i < 8; ++i) {
            int id = tid + i * 256;
            int b  = id >> 5;
            int k4 = id & 31;
            int tok = prob[b * SEQLEN + t];
            float4 v = *(const float4*)(embed + (size_t)tok * EMBED + kt * 128 + k4 * 4);
            *(float4*)(&xe[b * 132 + k4 * 4]) = v;
        }
        __syncthreads();
        #pragma unroll
        for (int i = 0; i < 8; ++i) {
            int id = tid + i * 256;
            int kl = id >> 4;
            int b4 = id & 15;
            float4 v;
            v.x = xe[(b4 * 4 + 0) * 132 + kl];
            v.y = xe[(b4 * 4 + 1) * 132 + kl];
            v.z = xe[(b4 * 4 + 2) * 132 + kl];
            v.w = xe[(b4 * 4 + 3) * 132 + kl];
            *(float4*)(&xT[((size_t)t * EMBED + kt * 128 + kl) * 64 + b4 * 4]) = v;
        }
        __syncthreads();
    }
}

__global__ __launch_bounds__(NTHR, 4) void lstm_persist_hist(
    const float* __restrict__ xT, float* __restrict__ h_hist,
    const float* __restrict__ cT,
    const float* __restrict__ w_ih, const float* __restrict__ w_hh,
    const float* __restrict__ b_ih, const float* __restrict__ b_hh,
    const float* __restrict__ w_ans, float* __restrict__ pout,
    int* __restrict__ bar)
{
    __shared__ float lds[LDS_FLOATS];
    const int tid = threadIdx.x;
    const int bid = blockIdx.x;
    const int b   = tid & 63;
    const int ksl = __builtin_amdgcn_readfirstlane(tid >> 6);
    const int u0  = bid * 2;

    int* sliceCnt = bar + (bid >> 6) * 32;
    int* mySlice  = bar + 256 + (bid >> 6) * 32;
    int* waitGo   = bar + 256 + ksl * 32;

    for (int idx = tid; idx < 12288; idx += NTHR) {
        int r  = idx / 1536;
        int k  = idx - r * 1536;
        int u2 = r & 1, gate = r >> 1;
        int row = gate * HID + u0 + u2;
        float v = (k < EMBED) ? w_ih[(size_t)row * EMBED + k]
                              : w_hh[(size_t)row * HID + (k - EMBED)];
        lds[(u2 * 1536 + k) * 4 + gate] = v;
    }
    if (tid < 128) lds[C_OFF + tid] = cT[u0 * 64 + tid];

    float bias[2][4], wans[2];
    #pragma unroll
    for (int uu = 0; uu < 2; ++uu) {
        #pragma unroll
        for (int j = 0; j < 4; ++j) {
            int rj = j * HID + u0 + uu;
            bias[uu][j] = b_ih[rj] + b_hh[rj];
        }
        wans[uu] = w_ans[u0 + uu];
    }
    __syncthreads();

    for (int t = 0; t < NSTEP; ++t) {
        const float* xt = xT + (size_t)t * EMBED * 64;
        const float* ht = h_hist + (size_t)t * HID * 64;
        float* hn_buf   = h_hist + (size_t)(t + 1) * HID * 64;

        float acc[2][4];
        #pragma unroll
        for (int uu = 0; uu < 2; ++uu)
            #pragma unroll
            for (int j = 0; j < 4; ++j) acc[uu][j] = 0.f;

        const int kx0 = ksl * 64;
        #pragma unroll 4
        for (int g = 0; g < 16; ++g) {
            const int k = kx0 + g * 4;
            float xv[4];
            #pragma unroll
            for (int i = 0; i < 4; ++i) xv[i] = xt[(size_t)(k + i) * 64 + b];
            #pragma unroll
            for (int i = 0; i < 4; ++i) {
                float4 wa = *(const float4*)&lds[(0 * 1536 + k + i) * 4];
                float4 wb = *(const float4*)&lds[(1 * 1536 + k + i) * 4];
                acc[0][0] = fmaf(wa.x, xv[i], acc[0][0]);
                acc[0][1] = fmaf(wa.y, xv[i], acc[0][1]);
                acc[0][2] = fmaf(wa.z, xv[i], acc[0][2]);
                acc[0][3] = fmaf(wa.w, xv[i], acc[0][3]);
                acc[1][0] = fmaf(wb.x, xv[i], acc[1][0]);
                acc[1][1] = fmaf(wb.y, xv[i], acc[1][1]);
                acc[1][2] = fmaf(wb.z, xv[i], acc[1][2]);
                acc[1][3] = fmaf(wb.w, xv[i], acc[1][3]);
            }
        }

        if (t > 0) {
            while (__hip_atomic_load(waitGo, __ATOMIC_RELAXED,
                                     __HIP_MEMORY_SCOPE_AGENT) < t)
                __builtin_amdgcn_s_sleep(4);
            __builtin_amdgcn_fence(__ATOMIC_ACQUIRE, "workgroup");
        }

        const int kh0 = ksl * 128;
        #pragma unroll 4
        for (int g = 0; g < 32; ++g) {
            const int kh = kh0 + g * 4;
            float hv[4];
            #pragma unroll
            for (int i = 0; i < 4; ++i)
                hv[i] = ht[(size_t)(kh + i) * 64 + b];
            #pragma unroll
            for (int i = 0; i < 4; ++i) {
                const int kw = EMBED + kh + i;
                float4 wa = *(const float4*)&lds[(0 * 1536 + kw) * 4];
                float4 wb = *(const float4*)&lds[(1 * 1536 + kw) * 4];
                acc[0][0] = fmaf(wa.x, hv[i], acc[0][0]);
                acc[0][1] = fmaf(wa.y, hv[i], acc[0][1]);
                acc[0][2] = fmaf(wa.z, hv[i], acc[0][2]);
                acc[0][3] = fmaf(wa.w, hv[i], acc[0][3]);
                acc[1][0] = fmaf(wb.x, hv[i], acc[1][0]);
                acc[1][1] = fmaf(wb.y, hv[i], acc[1][1]);
                acc[1][2] = fmaf(wb.z, hv[i], acc[1][2]);
                acc[1][3] = fmaf(wb.w, hv[i], acc[1][3]);
            }
        }

        if (ksl >= 4) {
            #pragma unroll
            for (int uu = 0; uu < 2; ++uu)
                #pragma unroll
                for (int j = 0; j < 4; ++j)
                    lds[REDA_OFF + (((ksl - 4) * 8) + uu * 4 + j) * 64 + b] = acc[uu][j];
        }
        __syncthreads();
        if (ksl < 4) {
            #pragma unroll
            for (int uu = 0; uu < 2; ++uu)
                #pragma unroll
                for (int j = 0; j < 4; ++j)
                    acc[uu][j] += lds[REDA_OFF + ((ksl * 8) + uu * 4 + j) * 64 + b];
        }
        if (ksl == 2 || ksl == 3) {
            #pragma unroll
            for (int uu = 0; uu < 2; ++uu)
                #pragma unroll
                for (int j = 0; j < 4; ++j)
                    lds[REDB_OFF + (((ksl - 2) * 8) + uu * 4 + j) * 64 + b] = acc[uu][j];
        }
        __syncthreads();
        if (ksl < 2) {
            #pragma unroll
            for (int uu = 0; uu < 2; ++uu)
                #pragma unroll
                for (int j = 0; j < 4; ++j)
                    acc[uu][j] += lds[REDB_OFF + ((ksl * 8) + uu * 4 + j) * 64 + b];
        }
        if (ksl == 0) {
            #pragma unroll
            for (int j = 0; j < 4; ++j)
                lds[REDC_OFF + j * 64 + b] = acc[1][j];
        }
        if (ksl == 1) {
            #pragma unroll
            for (int j = 0; j < 4; ++j)
                lds[REDC_OFF + (4 + j) * 64 + b] = acc[0][j];
        }
        __syncthreads();
        if (ksl < 2) {
            const int uu = ksl;
            float s[4];
            if (ksl == 0) {
                #pragma unroll
                for (int j = 0; j < 4; ++j)
                    s[j] = acc[0][j] + lds[REDC_OFF + (4 + j) * 64 + b];
            } else {
                #pragma unroll
                for (int j = 0; j < 4; ++j)
                    s[j] = acc[1][j] + lds[REDC_OFF + j * 64 + b];
            }
            float i_g = sigmoidf_(s[0] + bias[uu][0]);
            float f_g = sigmoidf_(s[1] + bias[uu][1]);
            float g_g = tanhf   (s[2] + bias[uu][2]);
            float o_g = sigmoidf_(s[3] + bias[uu][3]);
            float c_old = lds[C_OFF + uu * 64 + b];
            float c_new = f_g * c_old + i_g * g_g;
            float h_new = o_g * tanhf(c_new);
            lds[C_OFF + uu * 64 + b] = c_new;
            __hip_atomic_store(&hn_buf[(u0 + uu) * 64 + b], h_new,
                               __ATOMIC_RELAXED, __HIP_MEMORY_SCOPE_AGENT);
            lds[HEAD_OFF + uu * 64 + b] = h_new * wans[uu];
        }

        __syncthreads();
        if (t >= OUT0 && tid < 64) {
            pout[((size_t)(t - OUT0) * NBLK + bid) * 64 + tid] =
                lds[HEAD_OFF + tid] + lds[HEAD_OFF + 64 + tid];
        }
        if (t == NSTEP - 1) break;
        if (tid == 0) {
            int r = __hip_atomic_fetch_add(sliceCnt, 1, __ATOMIC_RELAXED,
                                           __HIP_MEMORY_SCOPE_AGENT);
            if (r == 64 * (t + 1) - 1)
                __hip_atomic_store(mySlice, t + 1, __ATOMIC_RELAXED,
                                   __HIP_MEMORY_SCOPE_AGENT);
        }
    }
}

__global__ __launch_bounds__(256) void finalize_persist(
    const float* __restrict__ pout, const float* __restrict__ b_ans,
    float* __restrict__ out)
{
    __shared__ float r[256];
    int col = blockIdx.x;
    int tid = threadIdx.x;
    int b = tid & 63, qq = tid >> 6;
    float s = 0.f;
    for (int i = qq; i < NBLK; i += 4)
        s += pout[((size_t)col * NBLK + i) * 64 + b];
    r[tid] = s;
    __syncthreads();
    if (tid < 64)
        out[tid * NOUT + col] = r[tid] + r[64 + tid] + r[128 + tid] + r[192 + tid]
                              + b_ans[0];
}

extern "C" void kernel_launch(void* const* d_in, const int* in_sizes, int n_in,
                              void* d_out, int out_size, void* d_ws, size_t ws_size,
                              hipStream_t stream)
{
    const int*   prob  = (const int*)  d_in[0];
    const float* embed = (const float*)d_in[2];
    const float* w_ih  = (const float*)d_in[3];
    const float* w_hh  = (const float*)d_in[4];
    const float* b_ih  = (const float*)d_in[5];
    const float* b_hh  = (const float*)d_in[6];
    const float* w_ans = (const float*)d_in[7];
    const float* b_ans = (const float*)d_in[8];
    const float* h0    = (const float*)d_in[9];
    const float* c0    = (const float*)d_in[10];

    // ---- fused-path ws layout (bytes), total 56,705,024 < proven 58.6 MB ----
    char* W = (char*)d_ws;
    float*    cT_m  = (float*)   (W);              //   262,144 B
    float*    poutm = (float*)   (W + 262144);     // 2,031,616 B  (62 x 128 x 64 f32)
    ushort_t* xf_hi = (ushort_t*)(W + 2293760);    // 8,323,072 B
    ushort_t* xf_lo = (ushort_t*)(W + 10616832);   // 8,323,072 B
    ushort_t* hf_hi = (ushort_t*)(W + 18939904);   // 16,777,216 B (full per-t history)
    ushort_t* hf_lo = (ushort_t*)(W + 35717120);   // 16,777,216 B
    float*    gx    = (float*)   (W + 52494336);   // 4,194,304 B  (R_GX=4 ring)
    int*      bar_m = (int*)     (W + 56688640);   //    16,384 B

    hipMemsetAsync(bar_m, 0, 16384, stream);
    init_mfma<<<256, 256, 0, stream>>>(h0, c0, cT_m, hf_hi, hf_lo);
    embed_frag<<<NSTEP, 256, 0, stream>>>(prob, embed, xf_hi, xf_lo);

    void* args[] = {
        (void*)&xf_hi, (void*)&xf_lo, (void*)&hf_hi, (void*)&hf_lo,
        (void*)&cT_m, (void*)&w_ih, (void*)&w_hh, (void*)&b_ih,
        (void*)&b_hh, (void*)&w_ans, (void*)&poutm, (void*)&gx, (void*)&bar_m
    };
    hipError_t err = hipLaunchCooperativeKernel((const void*)lstm_fused,
                                                dim3(256), dim3(512),
                                                args, 0, stream);
    if (err == hipSuccess) {
        finalize_mfma<<<NOUT, 256, 0, stream>>>(poutm, b_ans, (float*)d_out);
        return;
    }

    // ---- fallback: round-9 proven path (aliases the same ws region) ----
    float* ws     = (float*)d_ws;
    float* cT     = ws;                    // 65,536 fl
    float* pout   = ws + 65536;            // 2,031,616 fl
    float* xT     = ws + 2097152;          // 4,161,536 fl
    float* h_hist = ws + 6258688;          // 8,388,608 fl
    int*   bar    = (int*)(ws + 14647296);

    hipMemsetAsync(bar, 0, 2048, stream);
    init_state<<<256, 256, 0, stream>>>(h0, c0, h_hist, cT);
    embed_transpose<<<NSTEP, 256, 0, stream>>>(prob, embed, xT);

    void* args9[] = {
        (void*)&xT, (void*)&h_hist, (void*)&cT,
        (void*)&w_ih, (void*)&w_hh, (void*)&b_ih, (void*)&b_hh,
        (void*)&w_ans, (void*)&pout, (void*)&bar
    };
    hipLaunchCooperativeKernel((const void*)lstm_persist_hist,
                               dim3(NBLK), dim3(NTHR), args9, 0, stream);
    finalize_persist<<<NOUT, 256, 0, stream>>>(pout, b_ans, (float*)d_out);
}